// Round 3
// baseline (4079.451 us; speedup 1.0000x reference)
//
#include <hip/hip_runtime.h>
#include <math.h>

#define NN 4
#define FC 32
#define DC 32
#define HH 480
#define WW 640
#define hh 120
#define ww 160
#define RR 20
#define RG 10   // r values per block (2 groups)
#define TILE 14
#define ATT 16   // TILE+2 : conv1 output region (att pixels)
#define FT 18    // TILE+4 : feat / pooling region
#define BIAS_IDX 1282  // W//w//2 + (H//h//2)*W = 2 + 2*640
#define CP 16    // channel pairs (32 channels / 2)

// workspace layout (floats): [0..20) num[r], [20..40) den[r], [64..) w1t (9*32*32), then w2t (9*32*4)
#define WS_W1T 64
#define WS_W2T (WS_W1T + 9*32*32)

__device__ __forceinline__ unsigned int bf16pack(float a, float b) {
    unsigned int ua = __float_as_uint(a);
    ua = (ua + 0x7fffu + ((ua >> 16) & 1u)) >> 16;
    unsigned int ub = __float_as_uint(b);
    ub = (ub + 0x7fffu + ((ub >> 16) & 1u)) >> 16;
    return ua | (ub << 16);
}

__global__ void prep_kernel(const float* __restrict__ W_att, const float* __restrict__ W_post,
                            float* __restrict__ ws) {
    int tid = threadIdx.x;
    if (tid < 2*RR) ws[tid] = 0.f;
    float* w1t = ws + WS_W1T;
    float* w2t = ws + WS_W2T;
    // w1t[tap][c][oc] = W_att[oc][c][tap]   (OIHW input)
    for (int i = tid; i < 32*32*9; i += blockDim.x) {
        int oc = i / (32*9); int rem = i % (32*9); int c = rem / 9; int tap = rem % 9;
        w1t[(tap*32 + c)*32 + oc] = W_att[i];
    }
    // w2t[tap][c][oc2] = W_post[oc2][c][tap]
    for (int i = tid; i < 4*32*9; i += blockDim.x) {
        int oc = i / (32*9); int rem = i % (32*9); int c = rem / 9; int tap = rem % 9;
        w2t[(tap*32 + c)*4 + oc] = W_post[i];
    }
}

__launch_bounds__(256, 4)
__global__ void wvl_main(const float* __restrict__ x, const float* __restrict__ d,
                         const float* __restrict__ gts, const float* __restrict__ rnd,
                         const float* __restrict__ b_att, const float* __restrict__ b_post,
                         float* __restrict__ ws) {
    // bf16 channel-pair packed buffer. Phase A: feat [cp][FT*FT] (16*324 dwords).
    // Phase B (after barrier, reuses same memory): att*d [cp][ATT*ATT] (16*256 dwords).
    __shared__ unsigned int s_buf[CP * FT * FT];
    __shared__ float s_pgt[FT * FT];
    __shared__ int   s_pidx[FT * FT];
    __shared__ float s_rn[4], s_rd[4];

    const float* w1t = ws + WS_W1T;
    const float* w2t = ws + WS_W2T;
    float* numacc = ws;
    float* denacc = ws + RR;

    const int tid = threadIdx.x;
    const int tilesx = (ww + TILE - 1) / TILE;   // 12
    const int tx = blockIdx.x % tilesx;
    const int ty = blockIdx.x / tilesx;
    const int n  = blockIdx.y;

    const int py0 = ty * TILE - 2;   // pooling/feat region origin (18x18)
    const int px0 = tx * TILE - 2;

    const float* gt_n = gts + (size_t)n * HH * WW;
    const float* x_n  = x + (size_t)n * FC * HH * WW;

    // hoist d loads (invariant across r) into registers
    const int ay = tid >> 4, ax = tid & 15;
    float dval[32];
    {
        int gy = ty * TILE - 1 + ay;
        int gx = tx * TILE - 1 + ax;
        bool inb = (gy >= 0 && gy < hh && gx >= 0 && gx < ww);
        const float* d_n = d + (size_t)n * DC * hh * ww;
        #pragma unroll
        for (int c = 0; c < 32; ++c)
            dval[c] = inb ? d_n[(size_t)(c * hh + gy) * ww + gx] : 0.f;
    }

    for (int rr0 = 0; rr0 < RG; ++rr0) {
        const int r = blockIdx.z * RG + rr0;
        const float* rd_n = rnd + ((size_t)r * NN + n) * (size_t)(HH * WW);

        // ---------------- Stage 1: random pooling over the 18x18 region ----------------
        for (int p = tid; p < FT * FT; p += 256) {
            int pi = p / FT, pj = p % FT;
            int gi = py0 + pi, gj = px0 + pj;
            float gval = 0.f; int idx = -1;
            if (gi >= 0 && gi < hh && gj >= 0 && gj < ww) {
                float best = -1.f; int bii = 0, bjj = 0; float bg = 0.f;
                #pragma unroll
                for (int bi = 0; bi < 4; ++bi) {
                    const float* gr = gt_n + (size_t)(gi*4 + bi) * WW + gj*4;
                    const float* rp = rd_n + (size_t)(gi*4 + bi) * WW + gj*4;
                    #pragma unroll
                    for (int bj = 0; bj < 4; ++bj) {
                        float g  = gr[bj];
                        float rv = rp[bj];
                        float rm = (g > 0.1f) ? rv : 0.f;
                        if (rm > best) { best = rm; bii = bi; bjj = bj; bg = g; }
                    }
                }
                gval = bg;
                idx = (gi*4 + bii) * WW + (gj*4 + bjj) + BIAS_IDX;
            }
            s_pgt[p]  = gval;
            s_pidx[p] = idx;
        }
        __syncthreads();

        // ---------------- Stage 2: bilinear grid-sample feat (18x18 x 32c, bf16-pair) ----------------
        for (int p = tid; p < FT * FT; p += 256) {
            int idx = s_pidx[p];
            if (idx < 0) {
                #pragma unroll
                for (int cp = 0; cp < CP; ++cp) s_buf[cp * (FT*FT) + p] = 0u;
                continue;
            }
            int cc = idx % WW;
            int rr2 = idx / WW;
            // replicate reference float sequence
            float gxf = 2.0f * ((float)cc  / (float)WW - 0.5f);
            float gyf = 2.0f * ((float)rr2 / (float)HH - 0.5f);
            float ix = (gxf + 1.0f) * 0.5f * (float)(WW - 1);
            float iy = (gyf + 1.0f) * 0.5f * (float)(HH - 1);
            float x0f = floorf(ix), y0f = floorf(iy);
            float wx = ix - x0f, wy = iy - y0f;
            int x0 = (int)x0f, y0 = (int)y0f;
            float vx0 = (x0f >= 0.f        && x0f <= (float)(WW-1)) ? 1.f : 0.f;
            float vx1 = (x0f + 1.f >= 0.f  && x0f + 1.f <= (float)(WW-1)) ? 1.f : 0.f;
            float vy0 = (y0f >= 0.f        && y0f <= (float)(HH-1)) ? 1.f : 0.f;
            float vy1 = (y0f + 1.f >= 0.f  && y0f + 1.f <= (float)(HH-1)) ? 1.f : 0.f;
            int xi0 = min(max(x0, 0), WW-1),  xi1 = min(max(x0+1, 0), WW-1);
            int yi0 = min(max(y0, 0), HH-1),  yi1 = min(max(y0+1, 0), HH-1);
            float w00 = (1.f-wx)*(1.f-wy) * (vx0*vy0);
            float w10 = wx*(1.f-wy)       * (vx1*vy0);
            float w01 = (1.f-wx)*wy       * (vx0*vy1);
            float w11 = wx*wy             * (vx1*vy1);
            const float* p00 = x_n + (size_t)yi0 * WW + xi0;
            const float* p10 = x_n + (size_t)yi0 * WW + xi1;
            const float* p01 = x_n + (size_t)yi1 * WW + xi0;
            const float* p11 = x_n + (size_t)yi1 * WW + xi1;
            #pragma unroll 4
            for (int cp = 0; cp < CP; ++cp) {
                int o0 = (2*cp)     * (HH * WW);
                int o1 = (2*cp + 1) * (HH * WW);
                float f0 = w00 * p00[o0] + w10 * p10[o0] + w01 * p01[o0] + w11 * p11[o0];
                float f1 = w00 * p00[o1] + w10 * p10[o1] + w01 * p01[o1] + w11 * p11[o1];
                s_buf[cp * (FT*FT) + p] = bf16pack(f0, f1);
            }
        }
        __syncthreads();

        // ---------------- Stage 3: conv1 (32->32) + sigmoid + *d ----------------
        float acc[32];
        #pragma unroll
        for (int oc = 0; oc < 32; ++oc) acc[oc] = b_att[oc];

        for (int dy = 0; dy < 3; ++dy) {
            for (int dx = 0; dx < 3; ++dx) {
                const float* wt = w1t + (dy*3 + dx) * 1024;
                int base = (ay + dy) * FT + (ax + dx);
                for (int cp = 0; cp < CP; ++cp) {
                    unsigned int u = s_buf[cp * (FT*FT) + base];
                    float f0 = __uint_as_float(u << 16);
                    float f1 = __uint_as_float(u & 0xffff0000u);
                    const float* wp0 = wt + (2*cp) * 32;
                    const float* wp1 = wp0 + 32;
                    #pragma unroll
                    for (int oc = 0; oc < 32; ++oc) acc[oc] = fmaf(f0, wp0[oc], acc[oc]);
                    #pragma unroll
                    for (int oc = 0; oc < 32; ++oc) acc[oc] = fmaf(f1, wp1[oc], acc[oc]);
                }
            }
        }

        // all reads of feat done -> safe to repurpose s_buf for att*d after barrier
        __syncthreads();

        #pragma unroll
        for (int cp = 0; cp < CP; ++cp) {
            float a0 = 1.f / (1.f + __expf(-acc[2*cp]));
            float a1 = 1.f / (1.f + __expf(-acc[2*cp+1]));
            s_buf[cp * (ATT*ATT) + tid] = bf16pack(a0 * dval[2*cp], a1 * dval[2*cp+1]);
        }
        __syncthreads();

        // ---------------- Stage 4: conv2 (32->4) + log-grad targets + smooth-L1 ----------------
        float num_t = 0.f, den_t = 0.f;
        if (tid < TILE * TILE) {
            int qy = tid / TILE, qx = tid % TILE;
            int gy2 = ty * TILE + qy, gx2 = tx * TILE + qx;
            if (gy2 < hh && gx2 < ww) {
                float acc2[4];
                #pragma unroll
                for (int k = 0; k < 4; ++k) acc2[k] = b_post[k];
                for (int dy = 0; dy < 3; ++dy) {
                    for (int dx = 0; dx < 3; ++dx) {
                        const float* wt = w2t + (dy*3 + dx) * 128;
                        int base = (qy + dy) * ATT + (qx + dx);
                        for (int cp = 0; cp < CP; ++cp) {
                            unsigned int u = s_buf[cp * (ATT*ATT) + base];
                            float f0 = __uint_as_float(u << 16);
                            float f1 = __uint_as_float(u & 0xffff0000u);
                            const float* wp0 = wt + (2*cp) * 4;
                            const float* wp1 = wp0 + 4;
                            #pragma unroll
                            for (int k = 0; k < 4; ++k) acc2[k] = fmaf(f0, wp0[k], acc2[k]);
                            #pragma unroll
                            for (int k = 0; k < 4; ++k) acc2[k] = fmaf(f1, wp1[k], acc2[k]);
                        }
                    }
                }
                // pooling-region coords of this ds pixel: (qy+2, qx+2)
                int pc = (qy + 2) * FT + (qx + 2);
                float rgc = s_pgt[pc]; rgc = (rgc < 0.1f) ? 0.f : rgc;
                float lc = logf(rgc + 1e-6f);
                bool  mc = rgc > 0.1f;
                const int oys[4] = {0, 1, 1, 1};
                const int oxs[4] = {1, 1, 0, -1};
                #pragma unroll
                for (int k = 0; k < 4; ++k) {
                    int pnb = (qy + 2 + oys[k]) * FT + (qx + 2 + oxs[k]);
                    float rgn = s_pgt[pnb]; rgn = (rgn < 0.1f) ? 0.f : rgn;
                    float ln = logf(rgn + 1e-6f);
                    bool m = mc && (rgn > 0.1f);
                    float gg = lc - ln;
                    float a2 = fabsf(acc2[k] - gg);
                    float sl1 = (a2 < 0.01f) ? (0.5f * a2 * a2 / 0.01f) : (a2 - 0.005f);
                    if (m) { num_t += sl1; den_t += 1.f; }
                }
            }
        }

        // block reduction
        for (int off = 32; off > 0; off >>= 1) {
            num_t += __shfl_down(num_t, off);
            den_t += __shfl_down(den_t, off);
        }
        int wid = tid >> 6, lane = tid & 63;
        if (lane == 0) { s_rn[wid] = num_t; s_rd[wid] = den_t; }
        __syncthreads();
        if (tid == 0) {
            float tn = s_rn[0] + s_rn[1] + s_rn[2] + s_rn[3];
            float td = s_rd[0] + s_rd[1] + s_rd[2] + s_rd[3];
            atomicAdd(&numacc[r], tn);
            atomicAdd(&denacc[r], td);
        }
        __syncthreads();
    }
}

__global__ void finish_kernel(const float* __restrict__ ws, float* __restrict__ out) {
    if (threadIdx.x == 0 && blockIdx.x == 0) {
        float s = 0.f;
        for (int r = 0; r < RR; ++r) s += ws[r] / ws[RR + r];
        out[0] = s / (float)RR;
    }
}

extern "C" void kernel_launch(void* const* d_in, const int* in_sizes, int n_in,
                              void* d_out, int out_size, void* d_ws, size_t ws_size,
                              hipStream_t stream) {
    const float* x      = (const float*)d_in[0];
    const float* d      = (const float*)d_in[1];
    const float* gts    = (const float*)d_in[2];
    const float* rnd    = (const float*)d_in[3];
    const float* W_att  = (const float*)d_in[4];
    const float* b_att  = (const float*)d_in[5];
    const float* W_post = (const float*)d_in[6];
    const float* b_post = (const float*)d_in[7];
    float* out = (float*)d_out;
    float* ws  = (float*)d_ws;

    hipLaunchKernelGGL(prep_kernel, dim3(1), dim3(1024), 0, stream, W_att, W_post, ws);

    const int tilesx = (ww + TILE - 1) / TILE;  // 12
    const int tilesy = (hh + TILE - 1) / TILE;  // 9
    dim3 grid(tilesx * tilesy, NN, RR / RG);
    hipLaunchKernelGGL(wvl_main, grid, dim3(256), 0, stream,
                       x, d, gts, rnd, b_att, b_post, ws);

    hipLaunchKernelGGL(finish_kernel, dim3(1), dim3(64), 0, stream, ws, out);
}

// Round 4
// 1064.429 us; speedup vs baseline: 3.8325x; 3.8325x over previous
//
#include <hip/hip_runtime.h>
#include <math.h>

#define NN 4
#define FC 32
#define DC 32
#define HH 480
#define WW 640
#define hh 120
#define ww 160
#define RR 20
#define TILE 14
#define ATT 16   // TILE+2 : conv1 output region (att pixels)
#define FT 18    // TILE+4 : feat / pooling region
#define BIAS_IDX 1282  // W//w//2 + (H//h//2)*W = 2 + 2*640
#define CP 16    // channel pairs (32 channels / 2)

// workspace layout (dword units):
// [0..20) num[r], [20..40) den[r]
// [64 ..) w1t: 9*32*32 fp32
// [9280..) w2t: 9*32*4 fp32
// [16384..) rg   : RR*NN*hh*ww fp32          (1,536,000)
// [1552384..) pidx: RR*NN*hh*ww packed coords (1,536,000)
// [3088384..) xb  : NN*HH*WW*16 dwords (bf16 channel-pairs, channel-last)
#define WS_W1T 64
#define WS_W2T 9280
#define WS_RG  16384
#define WS_IDX 1552384
#define WS_XB  3088384
#define XB_COUNT ((size_t)NN * HH * WW * 16)
#define WS_NEED_BYTES (((size_t)WS_XB + XB_COUNT) * 4)

__device__ __forceinline__ unsigned int bf16pack(float a, float b) {
    unsigned int ua = __float_as_uint(a);
    ua = (ua + 0x7fffu + ((ua >> 16) & 1u)) >> 16;
    unsigned int ub = __float_as_uint(b);
    ub = (ub + 0x7fffu + ((ub >> 16) & 1u)) >> 16;
    return ua | (ub << 16);
}

__global__ void prep_kernel(const float* __restrict__ W_att, const float* __restrict__ W_post,
                            float* __restrict__ ws) {
    int tid = threadIdx.x;
    if (tid < 2*RR) ws[tid] = 0.f;
    float* w1t = ws + WS_W1T;
    float* w2t = ws + WS_W2T;
    for (int i = tid; i < 32*32*9; i += blockDim.x) {
        int oc = i / (32*9); int rem = i % (32*9); int c = rem / 9; int tap = rem % 9;
        w1t[(tap*32 + c)*32 + oc] = W_att[i];
    }
    for (int i = tid; i < 4*32*9; i += blockDim.x) {
        int oc = i / (32*9); int rem = i % (32*9); int c = rem / 9; int tap = rem % 9;
        w2t[(tap*32 + c)*4 + oc] = W_post[i];
    }
}

// x[n][c][y][:] fp32  ->  xb[n][y][x][cp] bf16-pair, channel-last (64B per pixel)
__global__ void xpack_kernel(const float* __restrict__ x, unsigned int* __restrict__ xb) {
    const int y = blockIdx.x;
    const int n = blockIdx.y;
    for (int px = threadIdx.x; px < WW; px += 256) {
        unsigned int* o = xb + ((size_t)(n*HH + y)*WW + px) * 16;
        uint4 v[4];
        #pragma unroll
        for (int k = 0; k < 4; ++k) {
            #pragma unroll
            for (int j = 0; j < 4; ++j) {
                int cp = 4*k + j;
                float f0 = x[((size_t)(n*FC + 2*cp    )*HH + y)*WW + px];
                float f1 = x[((size_t)(n*FC + 2*cp + 1)*HH + y)*WW + px];
                ((unsigned int*)&v[k])[j] = bf16pack(f0, f1);
            }
        }
        #pragma unroll
        for (int k = 0; k < 4; ++k) ((uint4*)o)[k] = v[k];
    }
}

// global random pooling: one thread per (h,w) cell
__global__ void pool_kernel(const float* __restrict__ gts, const float* __restrict__ rnd,
                            float* __restrict__ ws) {
    const int r = blockIdx.z, n = blockIdx.y;
    const int cell = blockIdx.x * 256 + threadIdx.x;   // < hh*ww = 19200
    const int h = cell / ww, w = cell % ww;
    const float* gt_n = gts + (size_t)n * HH * WW;
    const float* rd_n = rnd + ((size_t)r * NN + n) * (size_t)(HH * WW);
    float best = -1.f, bg = 0.f; int bii = 0, bjj = 0;
    #pragma unroll
    for (int bi = 0; bi < 4; ++bi) {
        const float4 g4 = *(const float4*)(gt_n + (size_t)(h*4 + bi)*WW + w*4);
        const float4 r4 = *(const float4*)(rd_n + (size_t)(h*4 + bi)*WW + w*4);
        const float gv[4] = {g4.x, g4.y, g4.z, g4.w};
        const float rv[4] = {r4.x, r4.y, r4.z, r4.w};
        #pragma unroll
        for (int bj = 0; bj < 4; ++bj) {
            float rm = (gv[bj] > 0.1f) ? rv[bj] : 0.f;
            if (rm > best) { best = rm; bii = bi; bjj = bj; bg = gv[bj]; }
        }
    }
    int idx_b = (h*4 + bii) * WW + (w*4 + bjj) + BIAS_IDX;
    size_t o = ((size_t)(r*NN + n) * (hh*ww)) + cell;
    ((float*)(ws + WS_RG))[o] = bg;
    ((unsigned int*)(ws + WS_IDX))[o] = ((unsigned int)(idx_b / WW) << 16) | (unsigned int)(idx_b % WW);
}

__launch_bounds__(256, 6)
__global__ void wvl_main(const unsigned int* __restrict__ xb, const float* __restrict__ d,
                         const float* __restrict__ b_att, const float* __restrict__ b_post,
                         float* __restrict__ ws) {
    __shared__ unsigned int s_buf[CP * FT * FT];
    __shared__ float s_pgt[FT * FT];
    __shared__ int   s_pidx[FT * FT];
    __shared__ float s_rn[4], s_rd[4];

    const float* w1t = ws + WS_W1T;
    const float* w2t = ws + WS_W2T;
    const float* rg_all  = (const float*)(ws + WS_RG);
    const unsigned int* pidx_all = (const unsigned int*)(ws + WS_IDX);

    const int tid = threadIdx.x;
    const int tilesx = (ww + TILE - 1) / TILE;   // 12
    const int tx = blockIdx.x % tilesx;
    const int ty = blockIdx.x / tilesx;
    const int n  = blockIdx.y;
    const int r  = blockIdx.z;

    const int py0 = ty * TILE - 2;
    const int px0 = tx * TILE - 2;

    // ------- Stage 1: load pooled tile (18x18) -------
    {
        const size_t base = (size_t)(r*NN + n) * (hh*ww);
        for (int p = tid; p < FT * FT; p += 256) {
            int pi = p / FT, pj = p % FT;
            int gi = py0 + pi, gj = px0 + pj;
            float gval = 0.f; int pk = -1;
            if (gi >= 0 && gi < hh && gj >= 0 && gj < ww) {
                size_t o = base + (size_t)gi * ww + gj;
                gval = rg_all[o];
                pk = (int)pidx_all[o];
            }
            s_pgt[p]  = gval;
            s_pidx[p] = pk;
        }
    }
    __syncthreads();

    // ------- Stage 2: bilinear gather from packed bf16 x (channel-last) -------
    for (int p = tid; p < FT * FT; p += 256) {
        int pk = s_pidx[p];
        if (pk < 0) {
            #pragma unroll
            for (int cp = 0; cp < CP; ++cp) s_buf[cp * (FT*FT) + p] = 0u;
            continue;
        }
        int rr2 = pk >> 16;
        int cc  = pk & 0xffff;
        float gxf = 2.0f * ((float)cc  / (float)WW - 0.5f);
        float gyf = 2.0f * ((float)rr2 / (float)HH - 0.5f);
        float ix = (gxf + 1.0f) * 0.5f * (float)(WW - 1);
        float iy = (gyf + 1.0f) * 0.5f * (float)(HH - 1);
        float x0f = floorf(ix), y0f = floorf(iy);
        float wx = ix - x0f, wy = iy - y0f;
        int x0 = (int)x0f, y0 = (int)y0f;
        float vx0 = (x0f >= 0.f        && x0f <= (float)(WW-1)) ? 1.f : 0.f;
        float vx1 = (x0f + 1.f >= 0.f  && x0f + 1.f <= (float)(WW-1)) ? 1.f : 0.f;
        float vy0 = (y0f >= 0.f        && y0f <= (float)(HH-1)) ? 1.f : 0.f;
        float vy1 = (y0f + 1.f >= 0.f  && y0f + 1.f <= (float)(HH-1)) ? 1.f : 0.f;
        int xi0 = min(max(x0, 0), WW-1),  xi1 = min(max(x0+1, 0), WW-1);
        int yi0 = min(max(y0, 0), HH-1),  yi1 = min(max(y0+1, 0), HH-1);
        float w00 = (1.f-wx)*(1.f-wy) * (vx0*vy0);
        float w10 = wx*(1.f-wy)       * (vx1*vy0);
        float w01 = (1.f-wx)*wy       * (vx0*vy1);
        float w11 = wx*wy             * (vx1*vy1);
        const uint4* q00 = (const uint4*)(xb + ((size_t)(n*HH + yi0)*WW + xi0) * 16);
        const uint4* q10 = (const uint4*)(xb + ((size_t)(n*HH + yi0)*WW + xi1) * 16);
        const uint4* q01 = (const uint4*)(xb + ((size_t)(n*HH + yi1)*WW + xi0) * 16);
        const uint4* q11 = (const uint4*)(xb + ((size_t)(n*HH + yi1)*WW + xi1) * 16);
        #pragma unroll
        for (int k = 0; k < 4; ++k) {
            uint4 A = q00[k], B = q10[k], C = q01[k], D = q11[k];
            #pragma unroll
            for (int j = 0; j < 4; ++j) {
                unsigned int ua = ((const unsigned int*)&A)[j];
                unsigned int ub = ((const unsigned int*)&B)[j];
                unsigned int uc = ((const unsigned int*)&C)[j];
                unsigned int ud = ((const unsigned int*)&D)[j];
                float f0 = w00 * __uint_as_float(ua << 16)
                         + w10 * __uint_as_float(ub << 16)
                         + w01 * __uint_as_float(uc << 16)
                         + w11 * __uint_as_float(ud << 16);
                float f1 = w00 * __uint_as_float(ua & 0xffff0000u)
                         + w10 * __uint_as_float(ub & 0xffff0000u)
                         + w01 * __uint_as_float(uc & 0xffff0000u)
                         + w11 * __uint_as_float(ud & 0xffff0000u);
                s_buf[(4*k + j) * (FT*FT) + p] = bf16pack(f0, f1);
            }
        }
    }
    __syncthreads();

    // ------- Stage 3: conv1 (32->32) + sigmoid + *d -------
    const int ay = tid >> 4, ax = tid & 15;
    float acc[32];
    #pragma unroll
    for (int oc = 0; oc < 32; ++oc) acc[oc] = b_att[oc];

    for (int dy = 0; dy < 3; ++dy) {
        for (int dx = 0; dx < 3; ++dx) {
            const float* wt = w1t + (dy*3 + dx) * 1024;
            int base = (ay + dy) * FT + (ax + dx);
            for (int cp = 0; cp < CP; ++cp) {
                unsigned int u = s_buf[cp * (FT*FT) + base];
                float f0 = __uint_as_float(u << 16);
                float f1 = __uint_as_float(u & 0xffff0000u);
                const float* wp0 = wt + (2*cp) * 32;
                const float* wp1 = wp0 + 32;
                #pragma unroll
                for (int oc = 0; oc < 32; ++oc) acc[oc] = fmaf(f0, wp0[oc], acc[oc]);
                #pragma unroll
                for (int oc = 0; oc < 32; ++oc) acc[oc] = fmaf(f1, wp1[oc], acc[oc]);
            }
        }
    }
    __syncthreads();

    {
        int gy = ty * TILE - 1 + ay;
        int gx = tx * TILE - 1 + ax;
        bool inb = (gy >= 0 && gy < hh && gx >= 0 && gx < ww);
        const float* d_n = d + (size_t)n * DC * hh * ww;
        #pragma unroll
        for (int cp = 0; cp < CP; ++cp) {
            float a0 = 1.f / (1.f + __expf(-acc[2*cp]));
            float a1 = 1.f / (1.f + __expf(-acc[2*cp+1]));
            float v0 = 0.f, v1 = 0.f;
            if (inb) {
                v0 = a0 * d_n[(size_t)((2*cp)   * hh + gy) * ww + gx];
                v1 = a1 * d_n[(size_t)((2*cp+1) * hh + gy) * ww + gx];
            }
            s_buf[cp * (ATT*ATT) + tid] = bf16pack(v0, v1);
        }
    }
    __syncthreads();

    // ------- Stage 4: conv2 (32->4) + log-grad targets + smooth-L1 -------
    float num_t = 0.f, den_t = 0.f;
    if (tid < TILE * TILE) {
        int qy = tid / TILE, qx = tid % TILE;
        int gy2 = ty * TILE + qy, gx2 = tx * TILE + qx;
        if (gy2 < hh && gx2 < ww) {
            float acc2[4];
            #pragma unroll
            for (int k = 0; k < 4; ++k) acc2[k] = b_post[k];
            for (int dy = 0; dy < 3; ++dy) {
                for (int dx = 0; dx < 3; ++dx) {
                    const float* wt = w2t + (dy*3 + dx) * 128;
                    int base = (qy + dy) * ATT + (qx + dx);
                    for (int cp = 0; cp < CP; ++cp) {
                        unsigned int u = s_buf[cp * (ATT*ATT) + base];
                        float f0 = __uint_as_float(u << 16);
                        float f1 = __uint_as_float(u & 0xffff0000u);
                        const float* wp0 = wt + (2*cp) * 4;
                        const float* wp1 = wp0 + 4;
                        #pragma unroll
                        for (int k2 = 0; k2 < 4; ++k2) acc2[k2] = fmaf(f0, wp0[k2], acc2[k2]);
                        #pragma unroll
                        for (int k2 = 0; k2 < 4; ++k2) acc2[k2] = fmaf(f1, wp1[k2], acc2[k2]);
                    }
                }
            }
            int pc = (qy + 2) * FT + (qx + 2);
            float rgc = s_pgt[pc]; rgc = (rgc < 0.1f) ? 0.f : rgc;
            float lc = logf(rgc + 1e-6f);
            bool  mc = rgc > 0.1f;
            const int oys[4] = {0, 1, 1, 1};
            const int oxs[4] = {1, 1, 0, -1};
            #pragma unroll
            for (int k = 0; k < 4; ++k) {
                int pnb = (qy + 2 + oys[k]) * FT + (qx + 2 + oxs[k]);
                float rgn = s_pgt[pnb]; rgn = (rgn < 0.1f) ? 0.f : rgn;
                float ln = logf(rgn + 1e-6f);
                bool m = mc && (rgn > 0.1f);
                float gg = lc - ln;
                float a2 = fabsf(acc2[k] - gg);
                float sl1 = (a2 < 0.01f) ? (0.5f * a2 * a2 / 0.01f) : (a2 - 0.005f);
                if (m) { num_t += sl1; den_t += 1.f; }
            }
        }
    }

    for (int off = 32; off > 0; off >>= 1) {
        num_t += __shfl_down(num_t, off);
        den_t += __shfl_down(den_t, off);
    }
    int wid = tid >> 6, lane = tid & 63;
    if (lane == 0) { s_rn[wid] = num_t; s_rd[wid] = den_t; }
    __syncthreads();
    if (tid == 0) {
        atomicAdd(&ws[r],      s_rn[0] + s_rn[1] + s_rn[2] + s_rn[3]);
        atomicAdd(&ws[RR + r], s_rd[0] + s_rd[1] + s_rd[2] + s_rd[3]);
    }
}

// ---------------- fallback (round-2 kernel, used if ws too small) ----------------
__launch_bounds__(256, 6)
__global__ void wvl_fallback(const float* __restrict__ x, const float* __restrict__ d,
                             const float* __restrict__ gts, const float* __restrict__ rnd,
                             const float* __restrict__ b_att, const float* __restrict__ b_post,
                             float* __restrict__ ws) {
    __shared__ unsigned int s_buf[CP * FT * FT];
    __shared__ float s_pgt[FT * FT];
    __shared__ int   s_pidx[FT * FT];
    __shared__ float s_rn[4], s_rd[4];

    const float* w1t = ws + WS_W1T;
    const float* w2t = ws + WS_W2T;

    const int tid = threadIdx.x;
    const int tilesx = (ww + TILE - 1) / TILE;
    const int tx = blockIdx.x % tilesx;
    const int ty = blockIdx.x / tilesx;
    const int n  = blockIdx.y;
    const int r  = blockIdx.z;
    const int py0 = ty * TILE - 2;
    const int px0 = tx * TILE - 2;

    const float* gt_n = gts + (size_t)n * HH * WW;
    const float* rd_n = rnd + ((size_t)r * NN + n) * (size_t)(HH * WW);
    for (int p = tid; p < FT * FT; p += 256) {
        int pi = p / FT, pj = p % FT;
        int gi = py0 + pi, gj = px0 + pj;
        float gval = 0.f; int idx = -1;
        if (gi >= 0 && gi < hh && gj >= 0 && gj < ww) {
            float best = -1.f; int bii = 0, bjj = 0; float bg = 0.f;
            #pragma unroll
            for (int bi = 0; bi < 4; ++bi) {
                const float* gr = gt_n + (size_t)(gi*4 + bi) * WW + gj*4;
                const float* rp = rd_n + (size_t)(gi*4 + bi) * WW + gj*4;
                #pragma unroll
                for (int bj = 0; bj < 4; ++bj) {
                    float g  = gr[bj];
                    float rv = rp[bj];
                    float rm = (g > 0.1f) ? rv : 0.f;
                    if (rm > best) { best = rm; bii = bi; bjj = bj; bg = g; }
                }
            }
            gval = bg;
            idx = (gi*4 + bii) * WW + (gj*4 + bjj) + BIAS_IDX;
        }
        s_pgt[p]  = gval;
        s_pidx[p] = idx;
    }
    __syncthreads();

    const float* x_n = x + (size_t)n * FC * HH * WW;
    for (int p = tid; p < FT * FT; p += 256) {
        int idx = s_pidx[p];
        if (idx < 0) {
            #pragma unroll
            for (int cp = 0; cp < CP; ++cp) s_buf[cp * (FT*FT) + p] = 0u;
            continue;
        }
        int cc = idx % WW;
        int rr2 = idx / WW;
        float gxf = 2.0f * ((float)cc  / (float)WW - 0.5f);
        float gyf = 2.0f * ((float)rr2 / (float)HH - 0.5f);
        float ix = (gxf + 1.0f) * 0.5f * (float)(WW - 1);
        float iy = (gyf + 1.0f) * 0.5f * (float)(HH - 1);
        float x0f = floorf(ix), y0f = floorf(iy);
        float wx = ix - x0f, wy = iy - y0f;
        int x0 = (int)x0f, y0 = (int)y0f;
        float vx0 = (x0f >= 0.f        && x0f <= (float)(WW-1)) ? 1.f : 0.f;
        float vx1 = (x0f + 1.f >= 0.f  && x0f + 1.f <= (float)(WW-1)) ? 1.f : 0.f;
        float vy0 = (y0f >= 0.f        && y0f <= (float)(HH-1)) ? 1.f : 0.f;
        float vy1 = (y0f + 1.f >= 0.f  && y0f + 1.f <= (float)(HH-1)) ? 1.f : 0.f;
        int xi0 = min(max(x0, 0), WW-1),  xi1 = min(max(x0+1, 0), WW-1);
        int yi0 = min(max(y0, 0), HH-1),  yi1 = min(max(y0+1, 0), HH-1);
        float w00 = (1.f-wx)*(1.f-wy) * (vx0*vy0);
        float w10 = wx*(1.f-wy)       * (vx1*vy0);
        float w01 = (1.f-wx)*wy       * (vx0*vy1);
        float w11 = wx*wy             * (vx1*vy1);
        const float* p00 = x_n + (size_t)yi0 * WW + xi0;
        const float* p10 = x_n + (size_t)yi0 * WW + xi1;
        const float* p01 = x_n + (size_t)yi1 * WW + xi0;
        const float* p11 = x_n + (size_t)yi1 * WW + xi1;
        #pragma unroll 4
        for (int cp = 0; cp < CP; ++cp) {
            int o0 = (2*cp)     * (HH * WW);
            int o1 = (2*cp + 1) * (HH * WW);
            float f0 = w00 * p00[o0] + w10 * p10[o0] + w01 * p01[o0] + w11 * p11[o0];
            float f1 = w00 * p00[o1] + w10 * p10[o1] + w01 * p01[o1] + w11 * p11[o1];
            s_buf[cp * (FT*FT) + p] = bf16pack(f0, f1);
        }
    }
    __syncthreads();

    const int ay = tid >> 4, ax = tid & 15;
    float acc[32];
    #pragma unroll
    for (int oc = 0; oc < 32; ++oc) acc[oc] = b_att[oc];
    for (int dy = 0; dy < 3; ++dy) {
        for (int dx = 0; dx < 3; ++dx) {
            const float* wt = w1t + (dy*3 + dx) * 1024;
            int base = (ay + dy) * FT + (ax + dx);
            for (int cp = 0; cp < CP; ++cp) {
                unsigned int u = s_buf[cp * (FT*FT) + base];
                float f0 = __uint_as_float(u << 16);
                float f1 = __uint_as_float(u & 0xffff0000u);
                const float* wp0 = wt + (2*cp) * 32;
                const float* wp1 = wp0 + 32;
                #pragma unroll
                for (int oc = 0; oc < 32; ++oc) acc[oc] = fmaf(f0, wp0[oc], acc[oc]);
                #pragma unroll
                for (int oc = 0; oc < 32; ++oc) acc[oc] = fmaf(f1, wp1[oc], acc[oc]);
            }
        }
    }
    __syncthreads();
    {
        int gy = ty * TILE - 1 + ay;
        int gx = tx * TILE - 1 + ax;
        bool inb = (gy >= 0 && gy < hh && gx >= 0 && gx < ww);
        const float* d_n = d + (size_t)n * DC * hh * ww;
        #pragma unroll
        for (int cp = 0; cp < CP; ++cp) {
            float a0 = 1.f / (1.f + __expf(-acc[2*cp]));
            float a1 = 1.f / (1.f + __expf(-acc[2*cp+1]));
            float v0 = 0.f, v1 = 0.f;
            if (inb) {
                v0 = a0 * d_n[(size_t)((2*cp)   * hh + gy) * ww + gx];
                v1 = a1 * d_n[(size_t)((2*cp+1) * hh + gy) * ww + gx];
            }
            s_buf[cp * (ATT*ATT) + tid] = bf16pack(v0, v1);
        }
    }
    __syncthreads();

    float num_t = 0.f, den_t = 0.f;
    if (tid < TILE * TILE) {
        int qy = tid / TILE, qx = tid % TILE;
        int gy2 = ty * TILE + qy, gx2 = tx * TILE + qx;
        if (gy2 < hh && gx2 < ww) {
            float acc2[4];
            #pragma unroll
            for (int k = 0; k < 4; ++k) acc2[k] = b_post[k];
            for (int dy = 0; dy < 3; ++dy) {
                for (int dx = 0; dx < 3; ++dx) {
                    const float* wt = w2t + (dy*3 + dx) * 128;
                    int base = (qy + dy) * ATT + (qx + dx);
                    for (int cp = 0; cp < CP; ++cp) {
                        unsigned int u = s_buf[cp * (ATT*ATT) + base];
                        float f0 = __uint_as_float(u << 16);
                        float f1 = __uint_as_float(u & 0xffff0000u);
                        const float* wp0 = wt + (2*cp) * 4;
                        const float* wp1 = wp0 + 4;
                        #pragma unroll
                        for (int k2 = 0; k2 < 4; ++k2) acc2[k2] = fmaf(f0, wp0[k2], acc2[k2]);
                        #pragma unroll
                        for (int k2 = 0; k2 < 4; ++k2) acc2[k2] = fmaf(f1, wp1[k2], acc2[k2]);
                    }
                }
            }
            int pc = (qy + 2) * FT + (qx + 2);
            float rgc = s_pgt[pc]; rgc = (rgc < 0.1f) ? 0.f : rgc;
            float lc = logf(rgc + 1e-6f);
            bool  mc = rgc > 0.1f;
            const int oys[4] = {0, 1, 1, 1};
            const int oxs[4] = {1, 1, 0, -1};
            #pragma unroll
            for (int k = 0; k < 4; ++k) {
                int pnb = (qy + 2 + oys[k]) * FT + (qx + 2 + oxs[k]);
                float rgn = s_pgt[pnb]; rgn = (rgn < 0.1f) ? 0.f : rgn;
                float ln = logf(rgn + 1e-6f);
                bool m = mc && (rgn > 0.1f);
                float gg = lc - ln;
                float a2 = fabsf(acc2[k] - gg);
                float sl1 = (a2 < 0.01f) ? (0.5f * a2 * a2 / 0.01f) : (a2 - 0.005f);
                if (m) { num_t += sl1; den_t += 1.f; }
            }
        }
    }
    for (int off = 32; off > 0; off >>= 1) {
        num_t += __shfl_down(num_t, off);
        den_t += __shfl_down(den_t, off);
    }
    int wid = tid >> 6, lane = tid & 63;
    if (lane == 0) { s_rn[wid] = num_t; s_rd[wid] = den_t; }
    __syncthreads();
    if (tid == 0) {
        atomicAdd(&ws[r],      s_rn[0] + s_rn[1] + s_rn[2] + s_rn[3]);
        atomicAdd(&ws[RR + r], s_rd[0] + s_rd[1] + s_rd[2] + s_rd[3]);
    }
}

__global__ void finish_kernel(const float* __restrict__ ws, float* __restrict__ out) {
    if (threadIdx.x == 0 && blockIdx.x == 0) {
        float s = 0.f;
        for (int r = 0; r < RR; ++r) s += ws[r] / ws[RR + r];
        out[0] = s / (float)RR;
    }
}

extern "C" void kernel_launch(void* const* d_in, const int* in_sizes, int n_in,
                              void* d_out, int out_size, void* d_ws, size_t ws_size,
                              hipStream_t stream) {
    const float* x      = (const float*)d_in[0];
    const float* d      = (const float*)d_in[1];
    const float* gts    = (const float*)d_in[2];
    const float* rnd    = (const float*)d_in[3];
    const float* W_att  = (const float*)d_in[4];
    const float* b_att  = (const float*)d_in[5];
    const float* W_post = (const float*)d_in[6];
    const float* b_post = (const float*)d_in[7];
    float* out = (float*)d_out;
    float* ws  = (float*)d_ws;

    hipLaunchKernelGGL(prep_kernel, dim3(1), dim3(1024), 0, stream, W_att, W_post, ws);

    const int tilesx = (ww + TILE - 1) / TILE;  // 12
    const int tilesy = (hh + TILE - 1) / TILE;  // 9
    dim3 grid(tilesx * tilesy, NN, RR);

    if (ws_size >= WS_NEED_BYTES) {
        unsigned int* xb = (unsigned int*)(ws + WS_XB);
        hipLaunchKernelGGL(xpack_kernel, dim3(HH, NN), dim3(256), 0, stream, x, xb);
        hipLaunchKernelGGL(pool_kernel, dim3(hh*ww/256, NN, RR), dim3(256), 0, stream, gts, rnd, ws);
        hipLaunchKernelGGL(wvl_main, grid, dim3(256), 0, stream, xb, d, b_att, b_post, ws);
    } else {
        hipLaunchKernelGGL(wvl_fallback, grid, dim3(256), 0, stream,
                           x, d, gts, rnd, b_att, b_post, ws);
    }

    hipLaunchKernelGGL(finish_kernel, dim3(1), dim3(64), 0, stream, ws, out);
}

// Round 5
// 691.335 us; speedup vs baseline: 5.9008x; 1.5397x over previous
//
#include <hip/hip_runtime.h>
#include <math.h>

#define NN 4
#define FC 32
#define DC 32
#define HH 480
#define WW 640
#define hh 120
#define ww 160
#define RR 20
#define TILE 14
#define ATT 16   // TILE+2 : conv1 output region (att pixels)
#define FT 18    // TILE+4 : feat / pooling region
#define BIAS_IDX 1282  // W//w//2 + (H//h//2)*W = 2 + 2*640
#define CP 16    // channel pairs (32 channels / 2)
#define PSTR 20  // dword stride per pixel in s_feat (16 data + 4 pad, keeps 16B align)
#define ASTR 257 // dword stride per channel-pair in attd overlay

// workspace layout (dword units):
// [0..20) num[r], [20..40) den[r]
// [64..)    w1t : 9*32*32 fp32      (fallback conv1)
// [9280..)  w2t : 9*32*4  fp32      (conv2)
// [10432..) wB1 : 9*2*64*4 dwords   (conv1 MFMA B-fragments, bf16 pairs)
// [16384..) rg   : RR*NN*hh*ww fp32
// [1552384..) pidx: RR*NN*hh*ww packed coords
// [3088384..) xb : NN*HH*WW*16 dwords (bf16 channel-pairs, channel-last)
#define WS_W1T 64
#define WS_W2T 9280
#define WS_WB1 10432
#define WS_RG  16384
#define WS_IDX 1552384
#define WS_XB  3088384
#define XB_COUNT ((size_t)NN * HH * WW * 16)
#define WS_NEED_BYTES (((size_t)WS_XB + XB_COUNT) * 4)

typedef __attribute__((ext_vector_type(8))) short short8;
typedef __attribute__((ext_vector_type(4))) float f32x4;

__device__ __forceinline__ unsigned int bf16pack(float a, float b) {
    unsigned int ua = __float_as_uint(a);
    ua = (ua + 0x7fffu + ((ua >> 16) & 1u)) >> 16;
    unsigned int ub = __float_as_uint(b);
    ub = (ub + 0x7fffu + ((ub >> 16) & 1u)) >> 16;
    return ua | (ub << 16);
}
__device__ __forceinline__ unsigned short bf16r(float f) {
    unsigned int u = __float_as_uint(f);
    u = (u + 0x7fffu + ((u >> 16) & 1u)) >> 16;
    return (unsigned short)u;
}

__global__ void prep_kernel(const float* __restrict__ W_att, const float* __restrict__ W_post,
                            float* __restrict__ ws) {
    int tid = threadIdx.x;
    if (tid < 2*RR) ws[tid] = 0.f;
    float* w1t = ws + WS_W1T;
    float* w2t = ws + WS_W2T;
    for (int i = tid; i < 32*32*9; i += blockDim.x) {
        int oc = i / (32*9); int rem = i % (32*9); int c = rem / 9; int tap = rem % 9;
        w1t[(tap*32 + c)*32 + oc] = W_att[i];
    }
    for (int i = tid; i < 4*32*9; i += blockDim.x) {
        int oc = i / (32*9); int rem = i % (32*9); int c = rem / 9; int tap = rem % 9;
        w2t[(tap*32 + c)*4 + oc] = W_post[i];
    }
    // conv1 MFMA B-fragments: B[k=c][n=oc] for 16x16x32 bf16.
    // lane: n = lane&15, k-slice = 8*(lane>>4)+j ; dword j packs (c0, c0+1)
    unsigned int* wb = (unsigned int*)(ws + WS_WB1);
    for (int i = tid; i < 9*2*64; i += blockDim.x) {
        int lane = i & 63; int th = i >> 6;
        int t = th >> 1, h2 = th & 1;
        int q = lane >> 4, col = lane & 15, oc = h2*16 + col;
        unsigned int vv[4];
        #pragma unroll
        for (int j = 0; j < 4; ++j) {
            int c0 = 8*q + 2*j;
            float f0 = W_att[(oc*32 + c0    )*9 + t];
            float f1 = W_att[(oc*32 + c0 + 1)*9 + t];
            vv[j] = bf16pack(f0, f1);
        }
        uint4 v4; v4.x = vv[0]; v4.y = vv[1]; v4.z = vv[2]; v4.w = vv[3];
        ((uint4*)wb)[i] = v4;
    }
}

// x[n][c][y][:] fp32  ->  xb[n][y][x][cp] bf16-pair, channel-last (64B per pixel)
__global__ void xpack_kernel(const float* __restrict__ x, unsigned int* __restrict__ xb) {
    const int y = blockIdx.x;
    const int n = blockIdx.y;
    for (int px = threadIdx.x; px < WW; px += 256) {
        unsigned int* o = xb + ((size_t)(n*HH + y)*WW + px) * 16;
        uint4 v[4];
        #pragma unroll
        for (int k = 0; k < 4; ++k) {
            #pragma unroll
            for (int j = 0; j < 4; ++j) {
                int cp = 4*k + j;
                float f0 = x[((size_t)(n*FC + 2*cp    )*HH + y)*WW + px];
                float f1 = x[((size_t)(n*FC + 2*cp + 1)*HH + y)*WW + px];
                ((unsigned int*)&v[k])[j] = bf16pack(f0, f1);
            }
        }
        #pragma unroll
        for (int k = 0; k < 4; ++k) ((uint4*)o)[k] = v[k];
    }
}

// global random pooling: one thread per (h,w) cell
__global__ void pool_kernel(const float* __restrict__ gts, const float* __restrict__ rnd,
                            float* __restrict__ ws) {
    const int r = blockIdx.z, n = blockIdx.y;
    const int cell = blockIdx.x * 256 + threadIdx.x;
    const int h = cell / ww, w = cell % ww;
    const float* gt_n = gts + (size_t)n * HH * WW;
    const float* rd_n = rnd + ((size_t)r * NN + n) * (size_t)(HH * WW);
    float best = -1.f, bg = 0.f; int bii = 0, bjj = 0;
    #pragma unroll
    for (int bi = 0; bi < 4; ++bi) {
        const float4 g4 = *(const float4*)(gt_n + (size_t)(h*4 + bi)*WW + w*4);
        const float4 r4 = *(const float4*)(rd_n + (size_t)(h*4 + bi)*WW + w*4);
        const float gv[4] = {g4.x, g4.y, g4.z, g4.w};
        const float rv[4] = {r4.x, r4.y, r4.z, r4.w};
        #pragma unroll
        for (int bj = 0; bj < 4; ++bj) {
            float rm = (gv[bj] > 0.1f) ? rv[bj] : 0.f;
            if (rm > best) { best = rm; bii = bi; bjj = bj; bg = gv[bj]; }
        }
    }
    int idx_b = (h*4 + bii) * WW + (w*4 + bjj) + BIAS_IDX;
    size_t o = ((size_t)(r*NN + n) * (hh*ww)) + cell;
    ((float*)(ws + WS_RG))[o] = bg;
    ((unsigned int*)(ws + WS_IDX))[o] = ((unsigned int)(idx_b / WW) << 16) | (unsigned int)(idx_b % WW);
}

__launch_bounds__(256, 4)
__global__ void wvl_main(const unsigned int* __restrict__ xb, const float* __restrict__ d,
                         const float* __restrict__ b_att, const float* __restrict__ b_post,
                         float* __restrict__ ws) {
    // s_feat: phase A = feat, channel-last [pix][PSTR] (16 data dwords/pixel).
    // phase B (overlay) = att*d, channel-pair planes stride ASTR.
    __shared__ unsigned int s_feat[FT * FT * PSTR];   // 6480 dwords = 25.9 KB
    __shared__ float s_pgt[FT * FT];
    __shared__ int   s_pidx[FT * FT];
    __shared__ float s_rn[4], s_rd[4];

    const float* w2t = ws + WS_W2T;
    const float* rg_all  = (const float*)(ws + WS_RG);
    const unsigned int* pidx_all = (const unsigned int*)(ws + WS_IDX);

    const int tid = threadIdx.x;
    const int tilesx = (ww + TILE - 1) / TILE;   // 12
    const int tx = blockIdx.x % tilesx;
    const int ty = blockIdx.x / tilesx;
    const int n  = blockIdx.y;
    const int r  = blockIdx.z;

    const int py0 = ty * TILE - 2;
    const int px0 = tx * TILE - 2;

    // ------- Stage 1: load pooled tile (18x18) -------
    {
        const size_t base = (size_t)(r*NN + n) * (hh*ww);
        for (int p = tid; p < FT * FT; p += 256) {
            int pi = p / FT, pj = p % FT;
            int gi = py0 + pi, gj = px0 + pj;
            float gval = 0.f; int pk = -1;
            if (gi >= 0 && gi < hh && gj >= 0 && gj < ww) {
                size_t o = base + (size_t)gi * ww + gj;
                gval = rg_all[o];
                pk = (int)pidx_all[o];
            }
            s_pgt[p]  = gval;
            s_pidx[p] = pk;
        }
    }
    __syncthreads();

    // ------- Stage 2: bilinear gather from packed bf16 x -> channel-last LDS -------
    for (int p = tid; p < FT * FT; p += 256) {
        int pk = s_pidx[p];
        unsigned int* dst = &s_feat[p * PSTR];
        if (pk < 0) {
            uint4 z; z.x = z.y = z.z = z.w = 0u;
            #pragma unroll
            for (int k = 0; k < 4; ++k) ((uint4*)dst)[k] = z;
            continue;
        }
        int rr2 = pk >> 16;
        int cc  = pk & 0xffff;
        float gxf = 2.0f * ((float)cc  / (float)WW - 0.5f);
        float gyf = 2.0f * ((float)rr2 / (float)HH - 0.5f);
        float ix = (gxf + 1.0f) * 0.5f * (float)(WW - 1);
        float iy = (gyf + 1.0f) * 0.5f * (float)(HH - 1);
        float x0f = floorf(ix), y0f = floorf(iy);
        float wx = ix - x0f, wy = iy - y0f;
        int x0 = (int)x0f, y0 = (int)y0f;
        float vx0 = (x0f >= 0.f        && x0f <= (float)(WW-1)) ? 1.f : 0.f;
        float vx1 = (x0f + 1.f >= 0.f  && x0f + 1.f <= (float)(WW-1)) ? 1.f : 0.f;
        float vy0 = (y0f >= 0.f        && y0f <= (float)(HH-1)) ? 1.f : 0.f;
        float vy1 = (y0f + 1.f >= 0.f  && y0f + 1.f <= (float)(HH-1)) ? 1.f : 0.f;
        int xi0 = min(max(x0, 0), WW-1),  xi1 = min(max(x0+1, 0), WW-1);
        int yi0 = min(max(y0, 0), HH-1),  yi1 = min(max(y0+1, 0), HH-1);
        float w00 = (1.f-wx)*(1.f-wy) * (vx0*vy0);
        float w10 = wx*(1.f-wy)       * (vx1*vy0);
        float w01 = (1.f-wx)*wy       * (vx0*vy1);
        float w11 = wx*wy             * (vx1*vy1);
        const uint4* q00 = (const uint4*)(xb + ((size_t)(n*HH + yi0)*WW + xi0) * 16);
        const uint4* q10 = (const uint4*)(xb + ((size_t)(n*HH + yi0)*WW + xi1) * 16);
        const uint4* q01 = (const uint4*)(xb + ((size_t)(n*HH + yi1)*WW + xi0) * 16);
        const uint4* q11 = (const uint4*)(xb + ((size_t)(n*HH + yi1)*WW + xi1) * 16);
        #pragma unroll
        for (int k = 0; k < 4; ++k) {
            uint4 A = q00[k], B = q10[k], C = q01[k], D = q11[k];
            uint4 o;
            #pragma unroll
            for (int j = 0; j < 4; ++j) {
                unsigned int ua = ((const unsigned int*)&A)[j];
                unsigned int ub = ((const unsigned int*)&B)[j];
                unsigned int uc = ((const unsigned int*)&C)[j];
                unsigned int ud = ((const unsigned int*)&D)[j];
                float f0 = w00 * __uint_as_float(ua << 16)
                         + w10 * __uint_as_float(ub << 16)
                         + w01 * __uint_as_float(uc << 16)
                         + w11 * __uint_as_float(ud << 16);
                float f1 = w00 * __uint_as_float(ua & 0xffff0000u)
                         + w10 * __uint_as_float(ub & 0xffff0000u)
                         + w01 * __uint_as_float(uc & 0xffff0000u)
                         + w11 * __uint_as_float(ud & 0xffff0000u);
                ((unsigned int*)&o)[j] = bf16pack(f0, f1);
            }
            ((uint4*)dst)[k] = o;
        }
    }
    __syncthreads();

    // ------- Stage 3: conv1 via MFMA 16x16x32 bf16 -------
    // wave wv handles att rows ay = wv*4 + rr. m = att col (lane&15), n = oc.
    const int lane = tid & 63;
    const int wv   = tid >> 6;
    const int mcol = lane & 15;
    const int q    = lane >> 4;

    f32x4 acc1[4][2];
    {
        float bb0 = b_att[mcol];
        float bb1 = b_att[mcol + 16];
        #pragma unroll
        for (int rr = 0; rr < 4; ++rr) {
            acc1[rr][0] = (f32x4){bb0, bb0, bb0, bb0};
            acc1[rr][1] = (f32x4){bb1, bb1, bb1, bb1};
        }
    }
    {
        const uint4* wB = (const uint4*)(ws + WS_WB1);
        #pragma unroll
        for (int t = 0; t < 9; ++t) {
            union { uint4 u; short8 s; } b0u, b1u;
            b0u.u = wB[(t*2 + 0)*64 + lane];
            b1u.u = wB[(t*2 + 1)*64 + lane];
            const int dy = t / 3, dx = t % 3;
            #pragma unroll
            for (int rr = 0; rr < 4; ++rr) {
                int ay = wv*4 + rr;
                int pix = (ay + dy) * FT + dx + mcol;
                union { uint4 u; short8 s; } a;
                a.u = *(const uint4*)&s_feat[pix * PSTR + 4*q];
                acc1[rr][0] = __builtin_amdgcn_mfma_f32_16x16x32_bf16(a.s, b0u.s, acc1[rr][0], 0, 0, 0);
                acc1[rr][1] = __builtin_amdgcn_mfma_f32_16x16x32_bf16(a.s, b1u.s, acc1[rr][1], 0, 0, 0);
            }
        }
    }
    __syncthreads();   // all feat reads done; s_feat can be overlaid with att*d

    // ------- Stage 3b: sigmoid + *d, write attd overlay -------
    // D layout: oc = lane&15 (+16h), ax = 4*q + reg, row ay = wv*4+rr
    {
        unsigned short* attd16 = (unsigned short*)s_feat;
        #pragma unroll
        for (int rr = 0; rr < 4; ++rr) {
            int ay = wv*4 + rr;
            int gy = ty * TILE - 1 + ay;
            bool gyok = (gy >= 0 && gy < hh);
            #pragma unroll
            for (int h2 = 0; h2 < 2; ++h2) {
                int oc = mcol + 16*h2;
                const float* drow = d + ((size_t)(n*DC + oc) * hh + (gyok ? gy : 0)) * ww;
                int cp = oc >> 1;
                int half = oc & 1;
                #pragma unroll
                for (int reg = 0; reg < 4; ++reg) {
                    int ax = 4*q + reg;
                    int gx = tx * TILE - 1 + ax;
                    float av = 1.f / (1.f + __expf(-acc1[rr][h2][reg]));
                    float dv = (gyok && gx >= 0 && gx < ww) ? drow[gx] : 0.f;
                    int pix = ay * ATT + ax;
                    attd16[(cp * ASTR + pix) * 2 + half] = bf16r(av * dv);
                }
            }
        }
    }
    __syncthreads();

    // ------- Stage 4: conv2 (32->4, VALU) + log-grad targets + smooth-L1 -------
    float num_t = 0.f, den_t = 0.f;
    if (tid < TILE * TILE) {
        int qy = tid / TILE, qx = tid % TILE;
        int gy2 = ty * TILE + qy, gx2 = tx * TILE + qx;
        if (gy2 < hh && gx2 < ww) {
            float acc2[4];
            #pragma unroll
            for (int k = 0; k < 4; ++k) acc2[k] = b_post[k];
            for (int dy = 0; dy < 3; ++dy) {
                for (int dx = 0; dx < 3; ++dx) {
                    const float* wt = w2t + (dy*3 + dx) * 128;
                    int base = (qy + dy) * ATT + (qx + dx);
                    for (int cp = 0; cp < CP; ++cp) {
                        unsigned int u = s_feat[cp * ASTR + base];
                        float f0 = __uint_as_float(u << 16);
                        float f1 = __uint_as_float(u & 0xffff0000u);
                        const float* wp0 = wt + (2*cp) * 4;
                        const float* wp1 = wp0 + 4;
                        #pragma unroll
                        for (int k2 = 0; k2 < 4; ++k2) acc2[k2] = fmaf(f0, wp0[k2], acc2[k2]);
                        #pragma unroll
                        for (int k2 = 0; k2 < 4; ++k2) acc2[k2] = fmaf(f1, wp1[k2], acc2[k2]);
                    }
                }
            }
            int pc = (qy + 2) * FT + (qx + 2);
            float rgc = s_pgt[pc]; rgc = (rgc < 0.1f) ? 0.f : rgc;
            float lc = logf(rgc + 1e-6f);
            bool  mc = rgc > 0.1f;
            const int oys[4] = {0, 1, 1, 1};
            const int oxs[4] = {1, 1, 0, -1};
            #pragma unroll
            for (int k = 0; k < 4; ++k) {
                int pnb = (qy + 2 + oys[k]) * FT + (qx + 2 + oxs[k]);
                float rgn = s_pgt[pnb]; rgn = (rgn < 0.1f) ? 0.f : rgn;
                float ln = logf(rgn + 1e-6f);
                bool m = mc && (rgn > 0.1f);
                float gg = lc - ln;
                float a2 = fabsf(acc2[k] - gg);
                float sl1 = (a2 < 0.01f) ? (0.5f * a2 * a2 / 0.01f) : (a2 - 0.005f);
                if (m) { num_t += sl1; den_t += 1.f; }
            }
        }
    }

    for (int off = 32; off > 0; off >>= 1) {
        num_t += __shfl_down(num_t, off);
        den_t += __shfl_down(den_t, off);
    }
    if (lane == 0) { s_rn[wv] = num_t; s_rd[wv] = den_t; }
    __syncthreads();
    if (tid == 0) {
        atomicAdd(&ws[r],      s_rn[0] + s_rn[1] + s_rn[2] + s_rn[3]);
        atomicAdd(&ws[RR + r], s_rd[0] + s_rd[1] + s_rd[2] + s_rd[3]);
    }
}

// ---------------- fallback (round-2 style, used if ws too small) ----------------
__launch_bounds__(256, 6)
__global__ void wvl_fallback(const float* __restrict__ x, const float* __restrict__ d,
                             const float* __restrict__ gts, const float* __restrict__ rnd,
                             const float* __restrict__ b_att, const float* __restrict__ b_post,
                             float* __restrict__ ws) {
    __shared__ unsigned int s_buf[CP * FT * FT];
    __shared__ float s_pgt[FT * FT];
    __shared__ int   s_pidx[FT * FT];
    __shared__ float s_rn[4], s_rd[4];

    const float* w1t = ws + WS_W1T;
    const float* w2t = ws + WS_W2T;

    const int tid = threadIdx.x;
    const int tilesx = (ww + TILE - 1) / TILE;
    const int tx = blockIdx.x % tilesx;
    const int ty = blockIdx.x / tilesx;
    const int n  = blockIdx.y;
    const int r  = blockIdx.z;
    const int py0 = ty * TILE - 2;
    const int px0 = tx * TILE - 2;

    const float* gt_n = gts + (size_t)n * HH * WW;
    const float* rd_n = rnd + ((size_t)r * NN + n) * (size_t)(HH * WW);
    for (int p = tid; p < FT * FT; p += 256) {
        int pi = p / FT, pj = p % FT;
        int gi = py0 + pi, gj = px0 + pj;
        float gval = 0.f; int idx = -1;
        if (gi >= 0 && gi < hh && gj >= 0 && gj < ww) {
            float best = -1.f; int bii = 0, bjj = 0; float bg = 0.f;
            #pragma unroll
            for (int bi = 0; bi < 4; ++bi) {
                const float* gr = gt_n + (size_t)(gi*4 + bi) * WW + gj*4;
                const float* rp = rd_n + (size_t)(gi*4 + bi) * WW + gj*4;
                #pragma unroll
                for (int bj = 0; bj < 4; ++bj) {
                    float g  = gr[bj];
                    float rv = rp[bj];
                    float rm = (g > 0.1f) ? rv : 0.f;
                    if (rm > best) { best = rm; bii = bi; bjj = bj; bg = g; }
                }
            }
            gval = bg;
            idx = (gi*4 + bii) * WW + (gj*4 + bjj) + BIAS_IDX;
        }
        s_pgt[p]  = gval;
        s_pidx[p] = idx;
    }
    __syncthreads();

    const float* x_n = x + (size_t)n * FC * HH * WW;
    for (int p = tid; p < FT * FT; p += 256) {
        int idx = s_pidx[p];
        if (idx < 0) {
            #pragma unroll
            for (int cp = 0; cp < CP; ++cp) s_buf[cp * (FT*FT) + p] = 0u;
            continue;
        }
        int cc = idx % WW;
        int rr2 = idx / WW;
        float gxf = 2.0f * ((float)cc  / (float)WW - 0.5f);
        float gyf = 2.0f * ((float)rr2 / (float)HH - 0.5f);
        float ix = (gxf + 1.0f) * 0.5f * (float)(WW - 1);
        float iy = (gyf + 1.0f) * 0.5f * (float)(HH - 1);
        float x0f = floorf(ix), y0f = floorf(iy);
        float wx = ix - x0f, wy = iy - y0f;
        int x0 = (int)x0f, y0 = (int)y0f;
        float vx0 = (x0f >= 0.f        && x0f <= (float)(WW-1)) ? 1.f : 0.f;
        float vx1 = (x0f + 1.f >= 0.f  && x0f + 1.f <= (float)(WW-1)) ? 1.f : 0.f;
        float vy0 = (y0f >= 0.f        && y0f <= (float)(HH-1)) ? 1.f : 0.f;
        float vy1 = (y0f + 1.f >= 0.f  && y0f + 1.f <= (float)(HH-1)) ? 1.f : 0.f;
        int xi0 = min(max(x0, 0), WW-1),  xi1 = min(max(x0+1, 0), WW-1);
        int yi0 = min(max(y0, 0), HH-1),  yi1 = min(max(y0+1, 0), HH-1);
        float w00 = (1.f-wx)*(1.f-wy) * (vx0*vy0);
        float w10 = wx*(1.f-wy)       * (vx1*vy0);
        float w01 = (1.f-wx)*wy       * (vx0*vy1);
        float w11 = wx*wy             * (vx1*vy1);
        const float* p00 = x_n + (size_t)yi0 * WW + xi0;
        const float* p10 = x_n + (size_t)yi0 * WW + xi1;
        const float* p01 = x_n + (size_t)yi1 * WW + xi0;
        const float* p11 = x_n + (size_t)yi1 * WW + xi1;
        #pragma unroll 4
        for (int cp = 0; cp < CP; ++cp) {
            int o0 = (2*cp)     * (HH * WW);
            int o1 = (2*cp + 1) * (HH * WW);
            float f0 = w00 * p00[o0] + w10 * p10[o0] + w01 * p01[o0] + w11 * p11[o0];
            float f1 = w00 * p00[o1] + w10 * p10[o1] + w01 * p01[o1] + w11 * p11[o1];
            s_buf[cp * (FT*FT) + p] = bf16pack(f0, f1);
        }
    }
    __syncthreads();

    const int ay = tid >> 4, ax = tid & 15;
    float acc[32];
    #pragma unroll
    for (int oc = 0; oc < 32; ++oc) acc[oc] = b_att[oc];
    for (int dy = 0; dy < 3; ++dy) {
        for (int dx = 0; dx < 3; ++dx) {
            const float* wt = w1t + (dy*3 + dx) * 1024;
            int base = (ay + dy) * FT + (ax + dx);
            for (int cp = 0; cp < CP; ++cp) {
                unsigned int u = s_buf[cp * (FT*FT) + base];
                float f0 = __uint_as_float(u << 16);
                float f1 = __uint_as_float(u & 0xffff0000u);
                const float* wp0 = wt + (2*cp) * 32;
                const float* wp1 = wp0 + 32;
                #pragma unroll
                for (int oc = 0; oc < 32; ++oc) acc[oc] = fmaf(f0, wp0[oc], acc[oc]);
                #pragma unroll
                for (int oc = 0; oc < 32; ++oc) acc[oc] = fmaf(f1, wp1[oc], acc[oc]);
            }
        }
    }
    __syncthreads();
    {
        int gy = ty * TILE - 1 + ay;
        int gx = tx * TILE - 1 + ax;
        bool inb = (gy >= 0 && gy < hh && gx >= 0 && gx < ww);
        const float* d_n = d + (size_t)n * DC * hh * ww;
        #pragma unroll
        for (int cp = 0; cp < CP; ++cp) {
            float a0 = 1.f / (1.f + __expf(-acc[2*cp]));
            float a1 = 1.f / (1.f + __expf(-acc[2*cp+1]));
            float v0 = 0.f, v1 = 0.f;
            if (inb) {
                v0 = a0 * d_n[(size_t)((2*cp)   * hh + gy) * ww + gx];
                v1 = a1 * d_n[(size_t)((2*cp+1) * hh + gy) * ww + gx];
            }
            s_buf[cp * (ATT*ATT) + tid] = bf16pack(v0, v1);
        }
    }
    __syncthreads();

    float num_t = 0.f, den_t = 0.f;
    if (tid < TILE * TILE) {
        int qy = tid / TILE, qx = tid % TILE;
        int gy2 = ty * TILE + qy, gx2 = tx * TILE + qx;
        if (gy2 < hh && gx2 < ww) {
            float acc2[4];
            #pragma unroll
            for (int k = 0; k < 4; ++k) acc2[k] = b_post[k];
            for (int dy = 0; dy < 3; ++dy) {
                for (int dx = 0; dx < 3; ++dx) {
                    const float* wt = w2t + (dy*3 + dx) * 128;
                    int base = (qy + dy) * ATT + (qx + dx);
                    for (int cp = 0; cp < CP; ++cp) {
                        unsigned int u = s_buf[cp * (ATT*ATT) + base];
                        float f0 = __uint_as_float(u << 16);
                        float f1 = __uint_as_float(u & 0xffff0000u);
                        const float* wp0 = wt + (2*cp) * 4;
                        const float* wp1 = wp0 + 4;
                        #pragma unroll
                        for (int k2 = 0; k2 < 4; ++k2) acc2[k2] = fmaf(f0, wp0[k2], acc2[k2]);
                        #pragma unroll
                        for (int k2 = 0; k2 < 4; ++k2) acc2[k2] = fmaf(f1, wp1[k2], acc2[k2]);
                    }
                }
            }
            int pc = (qy + 2) * FT + (qx + 2);
            float rgc = s_pgt[pc]; rgc = (rgc < 0.1f) ? 0.f : rgc;
            float lc = logf(rgc + 1e-6f);
            bool  mc = rgc > 0.1f;
            const int oys[4] = {0, 1, 1, 1};
            const int oxs[4] = {1, 1, 0, -1};
            #pragma unroll
            for (int k = 0; k < 4; ++k) {
                int pnb = (qy + 2 + oys[k]) * FT + (qx + 2 + oxs[k]);
                float rgn = s_pgt[pnb]; rgn = (rgn < 0.1f) ? 0.f : rgn;
                float ln = logf(rgn + 1e-6f);
                bool m = mc && (rgn > 0.1f);
                float gg = lc - ln;
                float a2 = fabsf(acc2[k] - gg);
                float sl1 = (a2 < 0.01f) ? (0.5f * a2 * a2 / 0.01f) : (a2 - 0.005f);
                if (m) { num_t += sl1; den_t += 1.f; }
            }
        }
    }
    for (int off = 32; off > 0; off >>= 1) {
        num_t += __shfl_down(num_t, off);
        den_t += __shfl_down(den_t, off);
    }
    int wid = tid >> 6, lane = tid & 63;
    if (lane == 0) { s_rn[wid] = num_t; s_rd[wid] = den_t; }
    __syncthreads();
    if (tid == 0) {
        atomicAdd(&ws[r],      s_rn[0] + s_rn[1] + s_rn[2] + s_rn[3]);
        atomicAdd(&ws[RR + r], s_rd[0] + s_rd[1] + s_rd[2] + s_rd[3]);
    }
}

__global__ void finish_kernel(const float* __restrict__ ws, float* __restrict__ out) {
    if (threadIdx.x == 0 && blockIdx.x == 0) {
        float s = 0.f;
        for (int r = 0; r < RR; ++r) s += ws[r] / ws[RR + r];
        out[0] = s / (float)RR;
    }
}

extern "C" void kernel_launch(void* const* d_in, const int* in_sizes, int n_in,
                              void* d_out, int out_size, void* d_ws, size_t ws_size,
                              hipStream_t stream) {
    const float* x      = (const float*)d_in[0];
    const float* d      = (const float*)d_in[1];
    const float* gts    = (const float*)d_in[2];
    const float* rnd    = (const float*)d_in[3];
    const float* W_att  = (const float*)d_in[4];
    const float* b_att  = (const float*)d_in[5];
    const float* W_post = (const float*)d_in[6];
    const float* b_post = (const float*)d_in[7];
    float* out = (float*)d_out;
    float* ws  = (float*)d_ws;

    hipLaunchKernelGGL(prep_kernel, dim3(1), dim3(1024), 0, stream, W_att, W_post, ws);

    const int tilesx = (ww + TILE - 1) / TILE;  // 12
    const int tilesy = (hh + TILE - 1) / TILE;  // 9
    dim3 grid(tilesx * tilesy, NN, RR);

    if (ws_size >= WS_NEED_BYTES) {
        unsigned int* xb = (unsigned int*)(ws + WS_XB);
        hipLaunchKernelGGL(xpack_kernel, dim3(HH, NN), dim3(256), 0, stream, x, xb);
        hipLaunchKernelGGL(pool_kernel, dim3(hh*ww/256, NN, RR), dim3(256), 0, stream, gts, rnd, ws);
        hipLaunchKernelGGL(wvl_main, grid, dim3(256), 0, stream, xb, d, b_att, b_post, ws);
    } else {
        hipLaunchKernelGGL(wvl_fallback, grid, dim3(256), 0, stream,
                           x, d, gts, rnd, b_att, b_post, ws);
    }

    hipLaunchKernelGGL(finish_kernel, dim3(1), dim3(64), 0, stream, ws, out);
}